// Round 1
// baseline (246.399 us; speedup 1.0000x reference)
//
#include <hip/hip_runtime.h>
#include <stdint.h>

typedef __attribute__((ext_vector_type(8))) short short8;
typedef __attribute__((ext_vector_type(4))) float f32x4;

#define NH 12
#define DH 64

__device__ __forceinline__ short f2bf(float f) {
  union { float f; uint32_t u; } x; x.f = f;
  uint32_t u = x.u + 0x7fffu + ((x.u >> 16) & 1u);
  return (short)(u >> 16);
}

__device__ __forceinline__ short8 cvt8(const float* __restrict__ src) {
  float4 a = *reinterpret_cast<const float4*>(src);
  float4 b = *reinterpret_cast<const float4*>(src + 4);
  short8 f;
  f[0] = f2bf(a.x); f[1] = f2bf(a.y); f[2] = f2bf(a.z); f[3] = f2bf(a.w);
  f[4] = f2bf(b.x); f[5] = f2bf(b.y); f[6] = f2bf(b.z); f[7] = f2bf(b.w);
  return f;
}

// One block per (row-block, group, sub-segment, head). 2 waves / 128 threads.
// M = dilated segment length (128 for groups 0/1, 32 for group 2).
template<int M>
__global__ __launch_bounds__(128)
void bsda_kernel(const float* __restrict__ Q, const float* __restrict__ K,
                 const float* __restrict__ V, float* __restrict__ Out) {
  constexpr int NT    = M / 16;                    // score t-tiles
  constexpr int NKK   = M / 32;                    // PV k-steps
  constexpr int NRT_W = M / 32;                    // q row-tiles per wave
  constexpr int CMASK = (M / 8 >= 8) ? 7 : (M / 8 - 1);

  __shared__ short Klds[M * 64];       // [t][d] bf16, chunk-XOR swizzled
  __shared__ short Vlds[64 * M];       // [d][t] bf16 (transposed), swizzled
  __shared__ short Plds[2 * 16 * M];   // per-wave P tile, swizzled

  const int bid = blockIdx.x;
  int rb, base, r, off, h;
  if (M == 128) {
    rb = bid / 24;
    const int rem = bid % 24;
    const int combo = rem >> 2, hl = rem & 3;
    if (combo < 4) { base = combo * 128;       r = 1; off = 0; h = hl; }
    else           { base = (combo - 4) * 256; r = 2; off = 1; h = 4 + hl; }
  } else {
    rb = bid / 16;
    const int rem = bid % 16;
    base = (rem >> 2) * 128; r = 4; off = 2; h = 8 + (rem & 3);
  }

  const int tid  = threadIdx.x;
  const int wave = tid >> 6;
  const int lane = tid & 63;
  const int lhi  = lane >> 4;
  const int llo  = lane & 15;
  const int rt0  = wave * NRT_W;              // first row-tile of this wave
  const int qbase = rb * 512 + base + off;

  f32x4 acc[NRT_W][4];
  #pragma unroll
  for (int a = 0; a < NRT_W; ++a)
    #pragma unroll
    for (int d = 0; d < 4; ++d) acc[a][d] = f32x4{0.f, 0.f, 0.f, 0.f};

  const int c0 = (rb - 2 < 0) ? 0 : rb - 2;
  const int c1 = (rb + 2 > 15) ? 15 : rb + 2;

  short* const Pw = &Plds[wave * 16 * M];

  for (int cb = c0; cb <= c1; ++cb) {
    __syncthreads();   // protect LDS from previous iteration's readers
    const int kvbase = cb * 512 + base + off;

    // ---- stage K: [t][d] bf16, 8-bf16 chunks, slot = chunk ^ (t&7) ----
    for (int u = tid; u < M * 8; u += 128) {
      const int t = u >> 3, c8 = u & 7;
      const int gpos = kvbase + r * t;
      const float* src = K + ((size_t)gpos * NH + h) * DH + c8 * 8;
      const int slot = c8 ^ (t & 7);
      *reinterpret_cast<short8*>(&Klds[t * 64 + slot * 8]) = cvt8(src);
    }
    // ---- stage V transposed: [d][t] bf16, slot = (t>>3) ^ (d&CMASK) ----
    for (int u = tid; u < 64 * (M / 2); u += 128) {
      const int tp = u >> 6, d = u & 63;    // lanes sweep d -> coalesced
      const int t = tp * 2;
      const int gpos = kvbase + r * t;
      const size_t idx = ((size_t)gpos * NH + h) * DH + d;
      const float f0 = V[idx];
      const float f1 = V[idx + (size_t)r * NH * DH];
      const uint32_t pk = (uint32_t)(uint16_t)f2bf(f0) |
                          ((uint32_t)(uint16_t)f2bf(f1) << 16);
      const int slot = (t >> 3) ^ (d & CMASK);
      *reinterpret_cast<uint32_t*>(&Vlds[d * M + slot * 8 + (t & 7)]) = pk;
    }
    __syncthreads();

    for (int rr = 0; rr < NRT_W; ++rr) {
      // Q A-fragments for this 16-row tile (fp32 global -> bf16)
      short8 qf[2];
      {
        const int qrow = (rt0 + rr) * 16 + llo;
        const int gpos = qbase + r * qrow;
        const float* src = Q + ((size_t)gpos * NH + h) * DH + lhi * 8;
        qf[0] = cvt8(src);
        qf[1] = cvt8(src + 32);
      }
      // ---- QK^T ----
      f32x4 sc[NT];
      #pragma unroll
      for (int tt = 0; tt < NT; ++tt) sc[tt] = f32x4{0.f, 0.f, 0.f, 0.f};
      #pragma unroll
      for (int kk = 0; kk < 2; ++kk) {
        const int cid = kk * 4 + lhi;
        #pragma unroll
        for (int tt = 0; tt < NT; ++tt) {
          const int t = tt * 16 + llo;
          const int slot = cid ^ (t & 7);
          short8 kf = *reinterpret_cast<short8*>(&Klds[t * 64 + slot * 8]);
          sc[tt] = __builtin_amdgcn_mfma_f32_16x16x32_bf16(qf[kk], kf, sc[tt], 0, 0, 0);
        }
      }
      // ---- softmax over t (per-pair full softmax; scale = 1/8) ----
      float mx[4] = {-3e38f, -3e38f, -3e38f, -3e38f};
      #pragma unroll
      for (int tt = 0; tt < NT; ++tt)
        #pragma unroll
        for (int i = 0; i < 4; ++i) {
          const float s = sc[tt][i] * 0.125f;
          sc[tt][i] = s;
          mx[i] = fmaxf(mx[i], s);
        }
      #pragma unroll
      for (int i = 0; i < 4; ++i) {
        mx[i] = fmaxf(mx[i], __shfl_xor(mx[i], 1));
        mx[i] = fmaxf(mx[i], __shfl_xor(mx[i], 2));
        mx[i] = fmaxf(mx[i], __shfl_xor(mx[i], 4));
        mx[i] = fmaxf(mx[i], __shfl_xor(mx[i], 8));
      }
      float sm[4] = {0.f, 0.f, 0.f, 0.f};
      #pragma unroll
      for (int tt = 0; tt < NT; ++tt)
        #pragma unroll
        for (int i = 0; i < 4; ++i) {
          const float p = exp2f((sc[tt][i] - mx[i]) * 1.44269504f);
          sc[tt][i] = p;
          sm[i] += p;
        }
      #pragma unroll
      for (int i = 0; i < 4; ++i) {
        sm[i] += __shfl_xor(sm[i], 1);
        sm[i] += __shfl_xor(sm[i], 2);
        sm[i] += __shfl_xor(sm[i], 4);
        sm[i] += __shfl_xor(sm[i], 8);
        sm[i] = 1.0f / sm[i];
      }
      // ---- P -> LDS (normalized, bf16), re-layout D-frag -> A-frag ----
      #pragma unroll
      for (int tt = 0; tt < NT; ++tt) {
        const int pcol = tt * 16 + llo;
        #pragma unroll
        for (int i = 0; i < 4; ++i) {
          const int prow = lhi * 4 + i;
          const int slot = (pcol >> 3) ^ (prow & CMASK);
          Pw[prow * M + slot * 8 + (pcol & 7)] = f2bf(sc[tt][i] * sm[i]);
        }
      }
      // ---- PV (accumulate across kk and across col blocks) ----
      #pragma unroll
      for (int kk = 0; kk < NKK; ++kk) {
        const int cid = kk * 4 + lhi;
        const int slotp = cid ^ (llo & CMASK);
        short8 pf = *reinterpret_cast<short8*>(&Pw[llo * M + slotp * 8]);
        #pragma unroll
        for (int dt = 0; dt < 4; ++dt) {
          const int d = dt * 16 + llo;
          const int slotv = cid ^ (d & CMASK);
          short8 vf = *reinterpret_cast<short8*>(&Vlds[d * M + slotv * 8]);
          acc[rr][dt] = __builtin_amdgcn_mfma_f32_16x16x32_bf16(pf, vf, acc[rr][dt], 0, 0, 0);
        }
      }
    }
  }

  // ---- write output (fp32). Non-dilated positions stay at memset 0. ----
  #pragma unroll
  for (int rr = 0; rr < NRT_W; ++rr) {
    #pragma unroll
    for (int i = 0; i < 4; ++i) {
      const int qrow = (rt0 + rr) * 16 + lhi * 4 + i;
      const int gpos = qbase + r * qrow;
      float* dst = Out + ((size_t)gpos * NH + h) * DH;
      #pragma unroll
      for (int dt = 0; dt < 4; ++dt)
        dst[dt * 16 + llo] = acc[rr][dt][i];
    }
  }
}

extern "C" void kernel_launch(void* const* d_in, const int* in_sizes, int n_in,
                              void* d_out, int out_size, void* d_ws, size_t ws_size,
                              hipStream_t stream) {
  const float* q = (const float*)d_in[0];
  const float* k = (const float*)d_in[1];
  const float* v = (const float*)d_in[2];
  float* out = (float*)d_out;

  hipMemsetAsync(out, 0, (size_t)out_size * sizeof(float), stream);

  // groups 0 (r=1) and 1 (r=2): m=128. 16 rb * (4+2 subsegs) * 4 heads = 384 blocks
  bsda_kernel<128><<<dim3(384), dim3(128), 0, stream>>>(q, k, v, out);
  // group 2 (r=4): m=32. 16 rb * 4 subsegs * 4 heads = 256 blocks
  bsda_kernel<32><<<dim3(256), dim3(128), 0, stream>>>(q, k, v, out);
}

// Round 3
// 182.404 us; speedup vs baseline: 1.3508x; 1.3508x over previous
//
#include <hip/hip_runtime.h>
#include <stdint.h>

typedef __attribute__((ext_vector_type(8))) short short8;
typedef __attribute__((ext_vector_type(4))) float f32x4;

#define NH 12
#define DH 64

__device__ __forceinline__ short f2bf(float f) {
  union { float f; uint32_t u; } x; x.f = f;
  uint32_t u = x.u + 0x7fffu + ((x.u >> 16) & 1u);
  return (short)(u >> 16);
}

__device__ __forceinline__ short8 cvt8(const float* __restrict__ src) {
  float4 a = *reinterpret_cast<const float4*>(src);
  float4 b = *reinterpret_cast<const float4*>(src + 4);
  short8 f;
  f[0] = f2bf(a.x); f[1] = f2bf(a.y); f[2] = f2bf(a.z); f[3] = f2bf(a.w);
  f[4] = f2bf(b.x); f[5] = f2bf(b.y); f[6] = f2bf(b.z); f[7] = f2bf(b.w);
  return f;
}

// Attention for ONE (row-block, col-block) pair, one dilated segment, one head.
// NW waves cooperate: stage K/V to LDS, then each wave owns M/(16*NW) q row-tiles.
// Output contribution is atomicAdd'ed (sum over col blocks happens in memory).
template<int M, int NW>
__device__ __forceinline__ void attend(
    const float* __restrict__ Q, const float* __restrict__ K,
    const float* __restrict__ V, float* __restrict__ Out,
    int qbase, int kvbase, int r, int h,
    int w /*wave in unit*/, int tidu /*thread in unit*/,
    short* __restrict__ Klds, short* __restrict__ Vlds, short* __restrict__ Pw)
{
  constexpr int NT    = M / 16;
  constexpr int NKK   = M / 32;
  constexpr int NRT   = M / (16 * NW);
  constexpr int CMASK = (M / 8 >= 8) ? 7 : (M / 8 - 1);

  const int lane = tidu & 63;
  const int lhi  = lane >> 4;
  const int llo  = lane & 15;

  // ---- stage K: [t][d] bf16, 8-bf16 chunks, slot = c8 ^ (t&7) ----
  for (int u = tidu; u < M * 8; u += NW * 64) {
    const int t = u >> 3, c8 = u & 7;
    const float* src = K + ((size_t)(kvbase + r * t) * NH + h) * DH + c8 * 8;
    const int slot = c8 ^ (t & 7);
    *reinterpret_cast<short8*>(&Klds[t * 64 + slot * 8]) = cvt8(src);
  }
  // ---- stage V transposed: [d][t] bf16, slot = (t>>3) ^ (d&CMASK) ----
  for (int u = tidu; u < 64 * (M / 2); u += NW * 64) {
    const int tp = u >> 6, d = u & 63;   // lanes sweep d -> coalesced
    const int t = tp * 2;
    const size_t idx = ((size_t)(kvbase + r * t) * NH + h) * DH + d;
    const float f0 = V[idx];
    const float f1 = V[idx + (size_t)r * NH * DH];
    const uint32_t pk = (uint32_t)(uint16_t)f2bf(f0) |
                        ((uint32_t)(uint16_t)f2bf(f1) << 16);
    const int slot = (t >> 3) ^ (d & CMASK);
    *reinterpret_cast<uint32_t*>(&Vlds[d * M + slot * 8 + (t & 7)]) = pk;
  }
  __syncthreads();

  for (int rr = 0; rr < NRT; ++rr) {
    const int rt = w * NRT + rr;
    // Q A-fragments for this 16-row tile (fp32 global -> bf16)
    short8 qf[2];
    {
      const int qrow = rt * 16 + llo;
      const float* src = Q + ((size_t)(qbase + r * qrow) * NH + h) * DH + lhi * 8;
      qf[0] = cvt8(src);
      qf[1] = cvt8(src + 32);
    }
    // ---- QK^T ----
    f32x4 sc[NT];
    #pragma unroll
    for (int tt = 0; tt < NT; ++tt) sc[tt] = f32x4{0.f, 0.f, 0.f, 0.f};
    #pragma unroll
    for (int kk = 0; kk < 2; ++kk) {
      const int cid = kk * 4 + lhi;
      #pragma unroll
      for (int tt = 0; tt < NT; ++tt) {
        const int t = tt * 16 + llo;
        const int slot = cid ^ (t & 7);
        short8 kf = *reinterpret_cast<short8*>(&Klds[t * 64 + slot * 8]);
        sc[tt] = __builtin_amdgcn_mfma_f32_16x16x32_bf16(qf[kk], kf, sc[tt], 0, 0, 0);
      }
    }
    // ---- softmax over t (full per-pair softmax; scale = 1/8) ----
    float mx[4] = {-3e38f, -3e38f, -3e38f, -3e38f};
    #pragma unroll
    for (int tt = 0; tt < NT; ++tt)
      #pragma unroll
      for (int i = 0; i < 4; ++i) {
        const float s = sc[tt][i] * 0.125f;
        sc[tt][i] = s;
        mx[i] = fmaxf(mx[i], s);
      }
    #pragma unroll
    for (int i = 0; i < 4; ++i) {
      mx[i] = fmaxf(mx[i], __shfl_xor(mx[i], 1));
      mx[i] = fmaxf(mx[i], __shfl_xor(mx[i], 2));
      mx[i] = fmaxf(mx[i], __shfl_xor(mx[i], 4));
      mx[i] = fmaxf(mx[i], __shfl_xor(mx[i], 8));
    }
    float sm[4] = {0.f, 0.f, 0.f, 0.f};
    #pragma unroll
    for (int tt = 0; tt < NT; ++tt)
      #pragma unroll
      for (int i = 0; i < 4; ++i) {
        const float p = exp2f((sc[tt][i] - mx[i]) * 1.44269504f);
        sc[tt][i] = p;
        sm[i] += p;
      }
    #pragma unroll
    for (int i = 0; i < 4; ++i) {
      sm[i] += __shfl_xor(sm[i], 1);
      sm[i] += __shfl_xor(sm[i], 2);
      sm[i] += __shfl_xor(sm[i], 4);
      sm[i] += __shfl_xor(sm[i], 8);
      sm[i] = 1.0f / sm[i];
    }
    // ---- P -> per-wave LDS (normalized, bf16), D-frag -> A-frag relayout ----
    #pragma unroll
    for (int tt = 0; tt < NT; ++tt) {
      const int pcol = tt * 16 + llo;
      #pragma unroll
      for (int i = 0; i < 4; ++i) {
        const int prow = lhi * 4 + i;
        const int slot = (pcol >> 3) ^ (prow & CMASK);
        Pw[prow * M + slot * 8 + (pcol & 7)] = f2bf(sc[tt][i] * sm[i]);
      }
    }
    // ---- PV ----
    f32x4 acc[4];
    #pragma unroll
    for (int dt = 0; dt < 4; ++dt) acc[dt] = f32x4{0.f, 0.f, 0.f, 0.f};
    #pragma unroll
    for (int kk = 0; kk < NKK; ++kk) {
      const int cid = kk * 4 + lhi;
      const int slotp = cid ^ (llo & CMASK);
      short8 pf = *reinterpret_cast<short8*>(&Pw[llo * M + slotp * 8]);
      #pragma unroll
      for (int dt = 0; dt < 4; ++dt) {
        const int d = dt * 16 + llo;
        const int slotv = cid ^ (d & CMASK);
        short8 vf = *reinterpret_cast<short8*>(&Vlds[d * M + slotv * 8]);
        acc[dt] = __builtin_amdgcn_mfma_f32_16x16x32_bf16(pf, vf, acc[dt], 0, 0, 0);
      }
    }
    // ---- accumulate into output (sum over col blocks via atomics) ----
    #pragma unroll
    for (int i = 0; i < 4; ++i) {
      const int qrow = rt * 16 + lhi * 4 + i;
      float* dst = Out + ((size_t)(qbase + r * qrow) * NH + h) * DH;
      #pragma unroll
      for (int dt = 0; dt < 4; ++dt)
        atomicAdd(&dst[dt * 16 + llo], acc[dt][i]);
    }
  }
}

// Grid sections (74 block-sparse pairs):
//   A: [0,1184)    group 0: r=1 off=0 heads 0-3, 4 subsegs of 128, M=128, NW=4
//   B: [1184,1776) group 1: r=2 off=1 heads 4-7, 2 subsegs of 256, M=128, NW=4
//   C: [1776,2368) group 2: r=4 off=2 heads 8-11, 4 subsegs of 128, M=32;
//                  two 2-wave units per block, one subseg each
__global__ __launch_bounds__(256)
void bsda_all(const float* __restrict__ Q, const float* __restrict__ K,
              const float* __restrict__ V, float* __restrict__ Out) {
  __shared__ short lds[24576];   // 48 KB
  const int bid = blockIdx.x;
  const int tid = threadIdx.x;

  int p, r, off, h, base;
  if (bid < 1184) {
    p = bid >> 4; const int rem = bid & 15;
    base = (rem >> 2) * 128; r = 1; off = 0; h = rem & 3;
  } else if (bid < 1776) {
    const int t = bid - 1184; p = t >> 3; const int rem = t & 7;
    base = (rem >> 2) * 256; r = 2; off = 1; h = 4 + (rem & 3);
  } else {
    const int t = bid - 1776; p = t >> 3; const int rem = t & 7;
    base = (rem >> 2) * 256;  // sub-seg pair base (sp*2*128)
    r = 4; off = 2; h = 8 + (rem & 3);
  }

  // decode pair index -> (row block, col block); window = rb-2..rb+2 clipped
  int rb = 0, cb = 0;
  {
    int cum = 0;
    for (int rr2 = 0; rr2 < 16; ++rr2) {
      const int cc0 = (rr2 - 2 < 0) ? 0 : rr2 - 2;
      const int cc1 = (rr2 + 2 > 15) ? 15 : rr2 + 2;
      const int cnt = cc1 - cc0 + 1;
      if (p < cum + cnt) { rb = rr2; cb = cc0 + (p - cum); break; }
      cum += cnt;
    }
  }

  if (bid < 1776) {
    const int qbase  = rb * 512 + base + off;
    const int kvbase = cb * 512 + base + off;
    attend<128, 4>(Q, K, V, Out, qbase, kvbase, r, h,
                   tid >> 6, tid,
                   lds, lds + 8192, lds + 16384 + (tid >> 6) * 2048);
  } else {
    const int unit = tid >> 7;           // which 2-wave unit
    const int tidu = tid & 127;
    const int ssb  = base + unit * 128;  // this unit's subseg base
    const int qbase  = rb * 512 + ssb + off;
    const int kvbase = cb * 512 + ssb + off;
    attend<32, 2>(Q, K, V, Out, qbase, kvbase, r, h,
                  (tid >> 6) & 1, tidu,
                  lds + unit * 4096, lds + unit * 4096 + 2048,
                  lds + 8192 + (tid >> 6) * 512);
  }
}

extern "C" void kernel_launch(void* const* d_in, const int* in_sizes, int n_in,
                              void* d_out, int out_size, void* d_ws, size_t ws_size,
                              hipStream_t stream) {
  const float* q = (const float*)d_in[0];
  const float* k = (const float*)d_in[1];
  const float* v = (const float*)d_in[2];
  float* out = (float*)d_out;

  hipMemsetAsync(out, 0, (size_t)out_size * sizeof(float), stream);
  bsda_all<<<dim3(2368), dim3(256), 0, stream>>>(q, k, v, out);
}